// Round 6
// baseline (454.890 us; speedup 1.0000x reference)
//
#include <hip/hip_runtime.h>
#include <hip/hip_bf16.h>
#include <stdint.h>

typedef short short8 __attribute__((ext_vector_type(8)));
typedef float f32x4 __attribute__((ext_vector_type(4)));
typedef float fvec4 __attribute__((ext_vector_type(4)));
typedef unsigned short us4 __attribute__((ext_vector_type(4)));
typedef unsigned short us8 __attribute__((ext_vector_type(8)));

static __device__ __forceinline__ unsigned short f2bf(float f) {
  union { float f; uint32_t u; } v; v.f = f;
  uint32_t u = v.u;
  return (unsigned short)((u + 0x7FFFu + ((u >> 16) & 1u)) >> 16);
}

static __device__ __forceinline__ float bf2f(unsigned short u) {
  union { uint32_t u; float f; } v; v.u = (uint32_t)u << 16;
  return v.f;
}

// fast ELU: __expf -> v_exp_f32. |err| ~1e-7, fine vs 2e-2 threshold.
static __device__ __forceinline__ float elu_f(float v) {
  return v > 0.0f ? v : __expf(v) - 1.0f;
}

// Pack all 4 weight matrices into MFMA B-fragment order (bf16), one launch.
// frag layout: dst[((nt*KT + kt)*64 + lane)*8 + i] = bf16(W[32kt + 8(lane>>4) + i][16nt + (lane&15)])
__global__ void pack_all_kernel(const float* __restrict__ W1a, const float* __restrict__ W1b,
                                const float* __restrict__ W2a, const float* __restrict__ W2b,
                                unsigned short* __restrict__ w1aP, unsigned short* __restrict__ w1bP,
                                unsigned short* __restrict__ w2aP, unsigned short* __restrict__ w2bP) {
  int p = blockIdx.x * blockDim.x + threadIdx.x;
  const float* W; unsigned short* dst; int KT, Nc, q;
  if (p < 65536)       { W = W1a; dst = w1aP; KT = 8;  Nc = 256; q = p; }
  else if (p < 131072) { W = W1b; dst = w1bP; KT = 8;  Nc = 256; q = p - 65536; }
  else if (p < 229376) { W = W2a; dst = w2aP; KT = 12; Nc = 256; q = p - 131072; }
  else                 { W = W2b; dst = w2bP; KT = 8;  Nc = 128; q = p - 229376; }
  int i = q & 7;
  int l = (q >> 3) & 63;
  int rest = q >> 9;
  int kt = rest % KT;
  int nt = rest / KT;
  dst[q] = f2bf(W[(size_t)(kt * 32 + (l >> 4) * 8 + i) * Nc + nt * 16 + (l & 15)]);
}

__global__ void hist_kernel(const int* __restrict__ col_idx, int* __restrict__ cnt, int E) {
  int i = blockIdx.x * blockDim.x + threadIdx.x;
  if (i < E) atomicAdd(&cnt[col_idx[i]], 1);
}

// single-launch scan: each thread serially owns a chunk of 25, one 1024-wide block scan.
__global__ __launch_bounds__(1024) void scan_kernel(const int* __restrict__ cnt,
                                                    int* __restrict__ startA,
                                                    int* __restrict__ offs, int N, int E) {
  __shared__ int partial[1024];
  const int t = threadIdx.x;
  const int chunk = (N + 1023) >> 10;
  const int base = t * chunk;
  int s = 0;
  for (int i = 0; i < chunk; ++i) {
    int idx = base + i;
    if (idx < N) s += cnt[idx];
  }
  partial[t] = s;
  __syncthreads();
  for (int o = 1; o < 1024; o <<= 1) {
    int a = (t >= o) ? partial[t - o] : 0;
    __syncthreads();
    partial[t] += a;
    __syncthreads();
  }
  int run = partial[t] - s;  // exclusive prefix of this chunk
  for (int i = 0; i < chunk; ++i) {
    int idx = base + i;
    if (idx < N) {
      startA[idx] = run;
      offs[idx] = run;
      run += cnt[idx];
    }
  }
  if (t == 0) startA[N] = E;
}

#define LDA 264  // 256 + 8 pad (bf16 elems); 528B row stride, 16B aligned
#define EB 128   // edges per block

// 128 edges/block, 8 waves: wave = (row-half rh, col-quadrant cq).
// Rank derived in-kernel via atomicAdd on offs (replaces rank prepass).
__global__ __launch_bounds__(512, 4) void edge_mlp_kernel(
    const float* __restrict__ x, const int* __restrict__ row_idx,
    const int* __restrict__ col_idx, const float* __restrict__ eattr,
    const float* __restrict__ b1a,
    const unsigned short* __restrict__ w1aP, const unsigned short* __restrict__ w1bP,
    int* __restrict__ offs, unsigned short* __restrict__ hsort) {
  __shared__ __align__(16) unsigned short As[EB * LDA];
  __shared__ int rowi[EB];
  __shared__ int aux[EB];
  const int t = threadIdx.x;
  const int e0 = blockIdx.x * EB;

  if (t < EB) {
    rowi[t] = row_idx[e0 + t];
    aux[t] = atomicAdd(&offs[col_idx[e0 + t]], 1);
  }

  const int w = t >> 6, l = t & 63;
  const int rh = w >> 2, cq = w & 3;
  const int lr = l & 15, lk = l >> 4;
  const unsigned short* B1 = w1aP + (size_t)(cq * 32) * 512 + (size_t)l * 8;
  const unsigned short* B2 = w1bP + (size_t)(cq * 32) * 512 + (size_t)l * 8;

  short8 bA[4], bB[4];
#pragma unroll
  for (int n = 0; n < 4; ++n) bA[n] = *(const short8*)(B1 + n * 4096);

  __syncthreads();

  // stage A: [128 edges][256 feats] as bf16 (x[row] | edge_attr)
  for (int idx = t; idx < EB * 64; idx += 512) {
    int e = idx >> 6, c4 = idx & 63;
    fvec4 v;
    if (c4 < 32)
      v = *(const fvec4*)(x + (size_t)rowi[e] * 128 + c4 * 4);
    else
      v = __builtin_nontemporal_load((const fvec4*)(eattr + (size_t)(e0 + e) * 128 + (c4 - 32) * 4));
    us4 o;
    o.x = f2bf(v.x); o.y = f2bf(v.y); o.z = f2bf(v.z); o.w = f2bf(v.w);
    *(us4*)(&As[e * LDA + c4 * 4]) = o;
  }
  __syncthreads();

  f32x4 acc[4][4];
  const f32x4 zero4 = {0.f, 0.f, 0.f, 0.f};
#pragma unroll
  for (int mt = 0; mt < 4; ++mt)
#pragma unroll
    for (int nt = 0; nt < 4; ++nt) acc[mt][nt] = zero4;

  // GEMM1: rows [rh*64, rh*64+64) x W1a cols [cq*64, cq*64+64), B double-buffered
#pragma unroll
  for (int kt = 0; kt < 8; ++kt) {
    short8* bc = (kt & 1) ? bB : bA;
    short8* bn = (kt & 1) ? bA : bB;
    if (kt < 7) {
#pragma unroll
      for (int n = 0; n < 4; ++n) bn[n] = *(const short8*)(B1 + n * 4096 + (kt + 1) * 512);
    }
    short8 a[4];
#pragma unroll
    for (int mt = 0; mt < 4; ++mt)
      a[mt] = *(const short8*)(&As[(rh * 64 + mt * 16 + lr) * LDA + kt * 32 + lk * 8]);
#pragma unroll
    for (int mt = 0; mt < 4; ++mt)
#pragma unroll
      for (int nt = 0; nt < 4; ++nt)
        acc[mt][nt] = __builtin_amdgcn_mfma_f32_16x16x32_bf16(a[mt], bc[nt], acc[mt][nt], 0, 0, 0);
  }

#pragma unroll
  for (int n = 0; n < 4; ++n) bA[n] = *(const short8*)(B2 + n * 4096);

  __syncthreads();

  // epilogue1: bias + ELU -> bf16 H (reuse As)
#pragma unroll
  for (int nt = 0; nt < 4; ++nt) {
    int col = cq * 64 + nt * 16 + lr;
    float bias = b1a[col];
#pragma unroll
    for (int mt = 0; mt < 4; ++mt)
#pragma unroll
      for (int j = 0; j < 4; ++j) {
        float v = elu_f(acc[mt][nt][j] + bias);
        As[(rh * 64 + mt * 16 + lk * 4 + j) * LDA + col] = f2bf(v);
      }
  }
  __syncthreads();

  // GEMM2: H[128,256] x W1b[256,256]
#pragma unroll
  for (int mt = 0; mt < 4; ++mt)
#pragma unroll
    for (int nt = 0; nt < 4; ++nt) acc[mt][nt] = zero4;
#pragma unroll
  for (int kt = 0; kt < 8; ++kt) {
    short8* bc = (kt & 1) ? bB : bA;
    short8* bn = (kt & 1) ? bA : bB;
    if (kt < 7) {
#pragma unroll
      for (int n = 0; n < 4; ++n) bn[n] = *(const short8*)(B2 + n * 4096 + (kt + 1) * 512);
    }
    short8 a[4];
#pragma unroll
    for (int mt = 0; mt < 4; ++mt)
      a[mt] = *(const short8*)(&As[(rh * 64 + mt * 16 + lr) * LDA + kt * 32 + lk * 8]);
#pragma unroll
    for (int mt = 0; mt < 4; ++mt)
#pragma unroll
      for (int nt = 0; nt < 4; ++nt)
        acc[mt][nt] = __builtin_amdgcn_mfma_f32_16x16x32_bf16(a[mt], bc[nt], acc[mt][nt], 0, 0, 0);
  }

  // epilogue2: h -> LDS (b1b deferred to node kernel), then coalesced 16B-row scatter
  __syncthreads();
#pragma unroll
  for (int nt = 0; nt < 4; ++nt) {
    int col = cq * 64 + nt * 16 + lr;
#pragma unroll
    for (int mt = 0; mt < 4; ++mt)
#pragma unroll
      for (int j = 0; j < 4; ++j)
        As[(rh * 64 + mt * 16 + lk * 4 + j) * LDA + col] = f2bf(acc[mt][nt][j]);
  }
  __syncthreads();
  for (int i = t; i < EB * 32; i += 512) {
    int row = i >> 5, g = i & 31;
    us8 v = *(const us8*)(&As[row * LDA + g * 8]);
    *(us8*)(hsort + (size_t)aux[row] * 256 + g * 8) = v;
  }
}

#define LDN 392  // 384 + 8 pad

// 64 nodes/block, 4 waves. Gather CSR rows (f32 accum), then MLP2.
__global__ __launch_bounds__(256, 3) void node_mlp_kernel(
    const float* __restrict__ x, const unsigned short* __restrict__ hsort,
    const int* __restrict__ startA, const float* __restrict__ b1b,
    const float* __restrict__ b2a, const float* __restrict__ b2b,
    const unsigned short* __restrict__ w2aP, const unsigned short* __restrict__ w2bP,
    float* __restrict__ out, int N) {
  __shared__ __align__(16) unsigned short As[64 * LDN];
  const int t = threadIdx.x;
  const int n0 = blockIdx.x * 64;

  const int w = t >> 6, l = t & 63;
  const int lr = l & 15, lk = l >> 4;
  const unsigned short* B1 = w2aP + (size_t)(w * 48) * 512 + (size_t)l * 8;
  const unsigned short* B2 = w2bP + (size_t)(w * 16) * 512 + (size_t)l * 8;

  short8 bA[4], bB[4];
#pragma unroll
  for (int n = 0; n < 4; ++n) bA[n] = *(const short8*)(B1 + n * 6144);

  // stage x part: cols [0,128)
  for (int idx = t; idx < 64 * 32; idx += 256) {
    int nn = idx >> 5, c4 = idx & 31;
    int node = n0 + nn;
    fvec4 v = {0.f, 0.f, 0.f, 0.f};
    if (node < N) v = *(const fvec4*)(x + (size_t)node * 128 + c4 * 4);
    us4 o;
    o.x = f2bf(v.x); o.y = f2bf(v.y); o.z = f2bf(v.z); o.w = f2bf(v.w);
    *(us4*)(&As[nn * LDN + c4 * 4]) = o;
  }

  // gather mean: wave w -> nodes [16w,16w+16); lane covers 8 cols (16B loads),
  // two rows in flight via lane half (l>>5); merge with shfl_xor(32).
  {
    const int c = l & 31;
    const int h = l >> 5;
    float bias[8];
#pragma unroll
    for (int i = 0; i < 8; ++i) bias[i] = b1b[c * 8 + i];

    for (int k = 0; k < 16; ++k) {
      int nn = w * 16 + k;
      int node = n0 + nn;
      float sum[8] = {0.f, 0.f, 0.f, 0.f, 0.f, 0.f, 0.f, 0.f};
      int cn = 0;
      if (node < N) {
        int s = startA[node], e = startA[node + 1];
        cn = e - s;
        for (int r = s + h; r < e; r += 2) {
          us8 hv = *(const us8*)(hsort + (size_t)r * 256 + c * 8);
#pragma unroll
          for (int i = 0; i < 8; ++i) sum[i] += bf2f(hv[i]);
        }
      }
#pragma unroll
      for (int i = 0; i < 8; ++i) sum[i] += __shfl_xor(sum[i], 32);
      float inv = cn > 0 ? 1.0f / (float)cn : 0.f;
      float gate = cn > 0 ? 1.f : 0.f;
      us8 o;
#pragma unroll
      for (int i = 0; i < 8; ++i) o[i] = f2bf(sum[i] * inv + gate * bias[i]);
      if (h == 0) *(us8*)(&As[nn * LDN + 128 + c * 8]) = o;
    }
  }
  __syncthreads();

  const f32x4 zero4 = {0.f, 0.f, 0.f, 0.f};
  f32x4 acc[4][4];
#pragma unroll
  for (int mt = 0; mt < 4; ++mt)
#pragma unroll
    for (int nt = 0; nt < 4; ++nt) acc[mt][nt] = zero4;

  // GEMM1: [64,384] x W2a[384,256]
#pragma unroll
  for (int kt = 0; kt < 12; ++kt) {
    short8* bc = (kt & 1) ? bB : bA;
    short8* bn = (kt & 1) ? bA : bB;
    if (kt < 11) {
#pragma unroll
      for (int n = 0; n < 4; ++n) bn[n] = *(const short8*)(B1 + n * 6144 + (kt + 1) * 512);
    }
    short8 a[4];
#pragma unroll
    for (int mt = 0; mt < 4; ++mt)
      a[mt] = *(const short8*)(&As[(mt * 16 + lr) * LDN + kt * 32 + lk * 8]);
#pragma unroll
    for (int mt = 0; mt < 4; ++mt)
#pragma unroll
      for (int nt = 0; nt < 4; ++nt)
        acc[mt][nt] = __builtin_amdgcn_mfma_f32_16x16x32_bf16(a[mt], bc[nt], acc[mt][nt], 0, 0, 0);
  }

#pragma unroll
  for (int n = 0; n < 2; ++n) bA[n] = *(const short8*)(B2 + n * 4096);

  __syncthreads();

  // epilogue1: bias + ELU -> H (reuse As, stride 264)
#pragma unroll
  for (int nt = 0; nt < 4; ++nt) {
    int col = w * 64 + nt * 16 + lr;
    float bias = b2a[col];
#pragma unroll
    for (int mt = 0; mt < 4; ++mt)
#pragma unroll
      for (int j = 0; j < 4; ++j) {
        float v = elu_f(acc[mt][nt][j] + bias);
        As[(mt * 16 + lk * 4 + j) * 264 + col] = f2bf(v);
      }
  }
  __syncthreads();

  // GEMM2: H[64,256] x W2b[256,128]; wave w owns cols [32w, 32w+32)
  f32x4 acc2[4][2];
#pragma unroll
  for (int mt = 0; mt < 4; ++mt)
#pragma unroll
    for (int nt = 0; nt < 2; ++nt) acc2[mt][nt] = zero4;
#pragma unroll
  for (int kt = 0; kt < 8; ++kt) {
    short8* bc = (kt & 1) ? bB : bA;
    short8* bn = (kt & 1) ? bA : bB;
    if (kt < 7) {
#pragma unroll
      for (int n = 0; n < 2; ++n) bn[n] = *(const short8*)(B2 + n * 4096 + (kt + 1) * 512);
    }
    short8 a[4];
#pragma unroll
    for (int mt = 0; mt < 4; ++mt)
      a[mt] = *(const short8*)(&As[(mt * 16 + lr) * 264 + kt * 32 + lk * 8]);
#pragma unroll
    for (int mt = 0; mt < 4; ++mt)
#pragma unroll
      for (int nt = 0; nt < 2; ++nt)
        acc2[mt][nt] = __builtin_amdgcn_mfma_f32_16x16x32_bf16(a[mt], bc[nt], acc2[mt][nt], 0, 0, 0);
  }

  // epilogue2: bias + store
#pragma unroll
  for (int nt = 0; nt < 2; ++nt) {
    int col = w * 32 + nt * 16 + lr;
    float bias = b2b[col];
#pragma unroll
    for (int mt = 0; mt < 4; ++mt)
#pragma unroll
      for (int j = 0; j < 4; ++j) {
        int node = n0 + mt * 16 + lk * 4 + j;
        if (node < N) out[(size_t)node * 128 + col] = acc2[mt][nt][j] + bias;
      }
  }
}

extern "C" void kernel_launch(void* const* d_in, const int* in_sizes, int n_in,
                              void* d_out, int out_size, void* d_ws, size_t ws_size,
                              hipStream_t stream) {
  const float* x = (const float*)d_in[0];
  const int* ei = (const int*)d_in[1];
  const float* eattr = (const float*)d_in[2];
  const float* W1a = (const float*)d_in[5];
  const float* b1a = (const float*)d_in[6];
  const float* W1b = (const float*)d_in[7];
  const float* b1b = (const float*)d_in[8];
  const float* W2a = (const float*)d_in[9];
  const float* b2a = (const float*)d_in[10];
  const float* W2b = (const float*)d_in[11];
  const float* b2b = (const float*)d_in[12];

  const int N = in_sizes[0] / 128;   // 25000
  const int E = in_sizes[2] / 128;   // 400000

  char* ws = (char*)d_ws;
  unsigned short* hsort = (unsigned short*)ws;
  size_t off = (size_t)E * 256 * 2;
  int* cntbuf = (int*)(ws + off); off += (size_t)N * 4;
  int* startA = (int*)(ws + off); off += (size_t)(N + 1) * 4;
  int* offs   = (int*)(ws + off); off += (size_t)N * 4;
  off = (off + 255) & ~(size_t)255;
  unsigned short* w1aP = (unsigned short*)(ws + off); off += 256 * 256 * 2;
  unsigned short* w1bP = (unsigned short*)(ws + off); off += 256 * 256 * 2;
  unsigned short* w2aP = (unsigned short*)(ws + off); off += 384 * 256 * 2;
  unsigned short* w2bP = (unsigned short*)(ws + off);

  (void)hipMemsetAsync(cntbuf, 0, (size_t)N * 4, stream);

  pack_all_kernel<<<1024, 256, 0, stream>>>(W1a, W1b, W2a, W2b, w1aP, w1bP, w2aP, w2bP);

  hist_kernel<<<(E + 255) / 256, 256, 0, stream>>>(ei + E, cntbuf, E);
  scan_kernel<<<1, 1024, 0, stream>>>(cntbuf, startA, offs, N, E);

  edge_mlp_kernel<<<E / EB, 512, 0, stream>>>(x, ei, ei + E, eattr, b1a, w1aP, w1bP,
                                              offs, hsort);

  node_mlp_kernel<<<(N + 63) / 64, 256, 0, stream>>>(x, hsort, startA, b1b, b2a, b2b,
                                                     w2aP, w2bP, (float*)d_out, N);
}